// Round 4
// baseline (425.301 us; speedup 1.0000x reference)
//
#include <hip/hip_runtime.h>
#include <hip/hip_fp16.h>

#define DIM 64
#define BSH 8            // bucket = row >> 8  (256 rows per bucket)
#define MAXNB 1024       // bucket-count cap (nn <= 256K)
#define NBLKA 256        // blocks in binning passes A1/A2
#define BKT_SLACK 1800   // per-bucket slack: 256 rows * 7 pad max + headroom
#define MAXT 11264       // max padded slots per bucket (44KB LDS)
#define CHUNK_MAX 12512  // LDS sort buffer capacity (chunk = 12500 for ne=3.2M)

// ---------- A1: per-block bucket histogram (LDS atomics only) ----------
__global__ void binA1(const int* __restrict__ row, int* __restrict__ blkhist,
                      int ne, int chunk, int nbk) {
    __shared__ int h[MAXNB];
    for (int k = threadIdx.x; k < nbk; k += blockDim.x) h[k] = 0;
    __syncthreads();
    int start = blockIdx.x * chunk, end = min(ne, start + chunk);
    for (int i = start + threadIdx.x; i < end; i += blockDim.x)
        atomicAdd(&h[row[i] >> BSH], 1);
    __syncthreads();
    for (int k = threadIdx.x; k < nbk; k += blockDim.x)
        blkhist[blockIdx.x * nbk + k] = h[k];
}

// ---------- R: per-bucket total over the 256 blocks (reduction) ----------
__global__ void binRsum(const int* __restrict__ blkhist, int* __restrict__ bktraw, int nbk) {
    __shared__ int s[NBLKA];
    int k = blockIdx.x;
    s[threadIdx.x] = blkhist[threadIdx.x * nbk + k];
    __syncthreads();
    for (int d = NBLKA / 2; d; d >>= 1) {
        if ((int)threadIdx.x < d) s[threadIdx.x] += s[threadIdx.x + d];
        __syncthreads();
    }
    if (threadIdx.x == 0) bktraw[k] = s[0];
}

// ---------- S: exclusive scan of slacked bucket sizes -> bucket bases ----------
__global__ void binS(const int* __restrict__ bktraw, int* __restrict__ bktbase, int nbk) {
    __shared__ int s[MAXNB];
    int v = 0;
    if ((int)threadIdx.x < nbk) v = (bktraw[threadIdx.x] + BKT_SLACK + 7) & ~7;
    s[threadIdx.x] = v;
    __syncthreads();
    for (int d = 1; d < MAXNB; d <<= 1) {
        int t = (threadIdx.x >= d) ? s[threadIdx.x - d] : 0;
        __syncthreads();
        s[threadIdx.x] += t;
        __syncthreads();
    }
    if ((int)threadIdx.x < nbk) bktbase[threadIdx.x] = s[threadIdx.x] - v;
}

// ---------- A2: block-local counting sort in LDS, COALESCED uint4 writes ----------
// bin is block-major: block b's edges, grouped by bucket, at bin[b*chunkp ...).
// Eliminates the scattered 4B global stores (R1 evidence: those cost ~100+ us).
__global__ void binA2_sort(const int* __restrict__ row, const int* __restrict__ col,
                           const int* __restrict__ blkhist, int* __restrict__ blkboff,
                           unsigned int* __restrict__ bin, int ne, int chunk, int chunkp,
                           int nbk) {
    __shared__ int hh[MAXNB];
    __shared__ int ts[256];
    __shared__ int bo[MAXNB];
    __shared__ alignas(16) unsigned int buf[CHUNK_MAX];
    int b = blockIdx.x;
    int t = threadIdx.x;
    for (int k = t; k < MAXNB; k += 256) hh[k] = (k < nbk) ? blkhist[b * nbk + k] : 0;
    __syncthreads();
    // exclusive scan of hh[0..1023]: thread t owns 4 consecutive elements
    int i0 = t * 4;
    int a0 = hh[i0], a1 = hh[i0 + 1], a2 = hh[i0 + 2], a3 = hh[i0 + 3];
    ts[t] = a0 + a1 + a2 + a3;
    __syncthreads();
    for (int d = 1; d < 256; d <<= 1) {
        int v = (t >= d) ? ts[t - d] : 0;
        __syncthreads();
        ts[t] += v;
        __syncthreads();
    }
    int pre = (t > 0) ? ts[t - 1] : 0;
    bo[i0] = pre;
    bo[i0 + 1] = pre + a0;
    bo[i0 + 2] = pre + a0 + a1;
    bo[i0 + 3] = pre + a0 + a1 + a2;
    __syncthreads();
    for (int k = t; k < nbk; k += 256) blkboff[b * nbk + k] = bo[k];
    __syncthreads();
    // scatter into LDS sort buffer (bo doubles as cursor after blkboff saved)
    int start = b * chunk, end = min(ne, start + chunk);
    for (int i = start + t; i < end; i += 256) {
        int r = row[i];
        int k = r >> BSH;
        int p = atomicAdd(&bo[k], 1);
        buf[p] = ((unsigned)(r & 255) << 24) | (unsigned)col[i];
    }
    __syncthreads();
    // coalesced copy-out
    int cntb = end - start;
    uint4* dst = (uint4*)(bin + (size_t)b * chunkp);
    const uint4* srcb = (const uint4*)buf;
    for (int i = t; i * 4 < cntb; i += 256) dst[i] = srcb[i];
}

// ---------- B: per-bucket CSR build; rows padded to x8 with sentinel col = nn ----------
__global__ void csr_build2(const unsigned int* __restrict__ bin, const int* __restrict__ blkhist,
                           const int* __restrict__ blkboff, const int* __restrict__ bktbase,
                           int* __restrict__ csr, int* __restrict__ cnt, int* __restrict__ roff,
                           float* __restrict__ dinv, float* __restrict__ sqd,
                           int nn, int nbk, int chunkp) {
    __shared__ int rc[256];
    __shared__ int sc[256];
    __shared__ int rcur[256];
    __shared__ int Tt;
    __shared__ alignas(16) int scsr[MAXT];
    int k = blockIdx.x;
    int t = threadIdx.x;
    int wave = t >> 6, lane = t & 63;
    int base = bktbase[k];
    rc[t] = 0;
    __syncthreads();
    // pass 1: count rows (wave-cooperative coalesced segment reads)
    for (int b = wave; b < NBLKA; b += 4) {
        int len = blkhist[b * nbk + k];
        const unsigned int* src = bin + (size_t)b * chunkp + blkboff[b * nbk + k];
        for (int i = lane; i < len; i += 64)
            atomicAdd(&rc[src[i] >> 24], 1);
    }
    __syncthreads();
    // scan of 8-padded row widths
    int w = (rc[t] + 7) & ~7;
    sc[t] = w;
    __syncthreads();
    for (int d = 1; d < 256; d <<= 1) {
        int v = (t >= d) ? sc[t - d] : 0;
        __syncthreads();
        sc[t] += v;
        __syncthreads();
    }
    int myoff = sc[t] - w;
    if (t == 255) Tt = sc[255];
    rcur[t] = myoff;
    int r = (k << BSH) + t;
    if (r < nn) {
        int d = rc[t];
        cnt[r] = d;
        roff[r] = base + myoff;
        dinv[r] = d > 0 ? rsqrtf((float)d) : 0.0f;
        sqd[r]  = d > 0 ? sqrtf((float)d)  : 0.0f;
    }
    __syncthreads();
    int T = Tt;
    for (int i = t; i < T; i += 256) scsr[i] = nn;   // sentinel -> zero row of y
    __syncthreads();
    // pass 2: place
    for (int b = wave; b < NBLKA; b += 4) {
        int len = blkhist[b * nbk + k];
        const unsigned int* src = bin + (size_t)b * chunkp + blkboff[b * nbk + k];
        for (int i = lane; i < len; i += 64) {
            unsigned u = src[i];
            int p = atomicAdd(&rcur[u >> 24], 1);
            scsr[p] = (int)(u & 0xFFFFFFu);
        }
    }
    __syncthreads();
    for (int i = t; i * 4 < T; i += 256)
        ((int4*)(csr + base))[i] = ((const int4*)scsr)[i];
}

// ---------- mark rows whose y2 is consumed: batch rows + their neighbors ----------
__global__ void mark_kernel(const int* __restrict__ cnt, const int* __restrict__ off,
                            const int* __restrict__ csr, const int* __restrict__ uidx,
                            const int* __restrict__ iidx, unsigned char* __restrict__ flag,
                            int nb, int nu) {
    int t = blockIdx.x * (blockDim.x >> 6) + (threadIdx.x >> 6);
    int lane = threadIdx.x & 63;
    if (t >= 2 * nb) return;
    int r = (t < nb) ? uidx[t] : nu + iidx[t - nb];
    if (lane == 0) flag[r] = 1;
    int e = cnt[r];
    const int* erow = csr + off[r];
    for (int j = lane; j < e; j += 64) flag[erow[j]] = 1;
}

// ---------- init: y0[r] = half(dinv[r] * emb[r]); row nn of BOTH buffers zeroed ----------
__global__ void init_y_kernel(const float2* __restrict__ ue2, const float2* __restrict__ ie2,
                              const float* __restrict__ dinv, __half2* __restrict__ ya,
                              __half2* __restrict__ yb, int nu, int nn) {
    int t = blockIdx.x * blockDim.x + threadIdx.x;
    if (t >= (nn + 1) * 32) return;
    int r = t >> 5;
    if (r >= nn) {   // sentinel zero row
        ya[t] = __floats2half2_rn(0.0f, 0.0f);
        yb[t] = __floats2half2_rn(0.0f, 0.0f);
        return;
    }
    float2 v = (r < nu) ? ue2[t] : ie2[t - nu * 32];
    float d = dinv[r];
    ya[t] = __floats2half2_rn(d * v.x, d * v.y);
}

// ---------- paired-half2 gather-SpMM: lane = (edge parity h, feature pair f) ----------
// One 64-lane gather fetches 2 edges x 32 half2 (256B). Rows are 8-padded with the
// sentinel zero row, so there is no tail code at all.
__global__ void spmm_half_kernel(const int* __restrict__ cnt, const int* __restrict__ off,
                                 const int* __restrict__ csr, const float* __restrict__ dinv,
                                 const __half2* __restrict__ y2, __half2* __restrict__ yn2,
                                 const unsigned char* __restrict__ flag, int nn) {
    int r = blockIdx.x * 4 + (threadIdx.x >> 6);
    if (r >= nn) return;
    if (flag && !flag[r]) return;
    int lane = threadIdx.x & 63;
    int h = lane >> 5;
    int f = lane & 31;
    int e = cnt[r];
    const int* erow = csr + off[r];
    float2 a0 = {0.f, 0.f}, a1 = {0.f, 0.f}, a2 = {0.f, 0.f}, a3 = {0.f, 0.f};
    for (int j = 0; j < e; j += 8) {
        int4 ca = *(const int4*)(erow + j);
        int4 cb = *(const int4*)(erow + j + 4);
        int c0 = h ? ca.y : ca.x;
        int c1 = h ? ca.w : ca.z;
        int c2 = h ? cb.y : cb.x;
        int c3 = h ? cb.w : cb.z;
        float2 p0 = __half22float2(y2[(size_t)c0 * 32 + f]);
        float2 p1 = __half22float2(y2[(size_t)c1 * 32 + f]);
        float2 p2 = __half22float2(y2[(size_t)c2 * 32 + f]);
        float2 p3 = __half22float2(y2[(size_t)c3 * 32 + f]);
        a0.x += p0.x; a0.y += p0.y;
        a1.x += p1.x; a1.y += p1.y;
        a2.x += p2.x; a2.y += p2.y;
        a3.x += p3.x; a3.y += p3.y;
    }
    float sx = (a0.x + a1.x) + (a2.x + a3.x);
    float sy = (a0.y + a1.y) + (a2.y + a3.y);
    sx += __shfl_xor(sx, 32);
    sy += __shfl_xor(sy, 32);
    if (h == 0) {
        float d = dinv[r];
        float d2 = d * d;
        yn2[(size_t)r * 32 + f] = __floats2half2_rn(d2 * sx, d2 * sy);
    }
}

// ---------- layer-3 restricted to the 2*nb batch rows, same paired structure ----------
__global__ void spmm_rows_acc_kernel(const int* __restrict__ cnt, const int* __restrict__ off,
                                     const int* __restrict__ csr, const float* __restrict__ dinv,
                                     const __half2* __restrict__ y2, const int* __restrict__ uidx,
                                     const int* __restrict__ iidx, float2* __restrict__ acc2,
                                     int nb, int nu) {
    int t = blockIdx.x * 4 + (threadIdx.x >> 6);
    if (t >= 2 * nb) return;
    int lane = threadIdx.x & 63;
    int h = lane >> 5;
    int f = lane & 31;
    int r = (t < nb) ? uidx[t] : nu + iidx[t - nb];
    int e = cnt[r];
    const int* erow = csr + off[r];
    float2 a0 = {0.f, 0.f}, a1 = {0.f, 0.f}, a2 = {0.f, 0.f}, a3 = {0.f, 0.f};
    for (int j = 0; j < e; j += 8) {
        int4 ca = *(const int4*)(erow + j);
        int4 cb = *(const int4*)(erow + j + 4);
        int c0 = h ? ca.y : ca.x;
        int c1 = h ? ca.w : ca.z;
        int c2 = h ? cb.y : cb.x;
        int c3 = h ? cb.w : cb.z;
        float2 p0 = __half22float2(y2[(size_t)c0 * 32 + f]);
        float2 p1 = __half22float2(y2[(size_t)c1 * 32 + f]);
        float2 p2 = __half22float2(y2[(size_t)c2 * 32 + f]);
        float2 p3 = __half22float2(y2[(size_t)c3 * 32 + f]);
        a0.x += p0.x; a0.y += p0.y;
        a1.x += p1.x; a1.y += p1.y;
        a2.x += p2.x; a2.y += p2.y;
        a3.x += p3.x; a3.y += p3.y;
    }
    float sx = (a0.x + a1.x) + (a2.x + a3.x);
    float sy = (a0.y + a1.y) + (a2.y + a3.y);
    sx += __shfl_xor(sx, 32);
    sy += __shfl_xor(sy, 32);
    if (h == 0) {
        float d = dinv[r];
        float2 v = acc2[(size_t)t * 32 + f];
        v.x += d * sx;
        v.y += d * sy;
        acc2[(size_t)t * 32 + f] = v;
    }
}

// ---------- layer-0 acc: read embeddings directly (fp32 exact), first write ----------
__global__ void gather_acc0(const float* __restrict__ ue, const float* __restrict__ ie,
                            const int* __restrict__ uidx, const int* __restrict__ iidx,
                            float* __restrict__ acc, int nb, int nu) {
    int t = blockIdx.x * blockDim.x + threadIdx.x;
    int b = t >> 6;
    int lane = t & 63;
    if (b < nb) acc[t] = ue[(long)uidx[b] * DIM + lane];
    else if (b < 2 * nb) acc[t] = ie[(long)iidx[b - nb] * DIM + lane];
}

// ---------- layers 1,2 acc: x_l[r] = y_l[r] * sqrt(deg_r), half2-vectorized ----------
__global__ void gather_acc_y(const __half2* __restrict__ y2, const float* __restrict__ sqd,
                             const int* __restrict__ uidx, const int* __restrict__ iidx,
                             float2* __restrict__ acc2, int nb, int nu) {
    int t = blockIdx.x * blockDim.x + threadIdx.x;
    if (t >= 2 * nb * 32) return;
    int b = t >> 5;
    int r = (b < nb) ? uidx[b] : nu + iidx[b - nb];
    float s = sqd[r];
    float2 v = __half22float2(y2[(size_t)r * 32 + (t & 31)]);
    float2 a = acc2[t];
    a.x += v.x * s;
    a.y += v.y * s;
    acc2[t] = a;
}

// scores[b] = dot(acc_u[b], acc_i[b]) / 16
__global__ void scores_kernel(const float* __restrict__ acc, float* __restrict__ out, int nb) {
    int b = blockIdx.x * (blockDim.x >> 6) + (threadIdx.x >> 6);
    int lane = threadIdx.x & 63;
    if (b >= nb) return;
    float p = acc[(long)b * DIM + lane] * acc[(long)(nb + b) * DIM + lane];
    #pragma unroll
    for (int off = 32; off; off >>= 1) p += __shfl_down(p, off);
    if (lane == 0) out[b] = p * 0.0625f;
}

extern "C" void kernel_launch(void* const* d_in, const int* in_sizes, int n_in,
                              void* d_out, int out_size, void* d_ws, size_t ws_size,
                              hipStream_t stream) {
    const float* user_emb = (const float*)d_in[0];
    const float* item_emb = (const float*)d_in[1];
    const int* edge_row = (const int*)d_in[2];
    const int* edge_col = (const int*)d_in[3];
    const int* user_idx = (const int*)d_in[4];
    const int* item_idx = (const int*)d_in[5];
    float* out = (float*)d_out;

    const int nu = in_sizes[0] / DIM;   // 100000
    const int ni = in_sizes[1] / DIM;   // 50000
    const int nn = nu + ni;             // 150000
    const int ne = in_sizes[2];         // 3200000
    const int nb = in_sizes[4];         // 4096

    const int nbk = (nn + 255) >> BSH;              // 586 buckets
    const int chunk = (ne + NBLKA - 1) / NBLKA;     // 12500
    const int chunkp = (chunk + 3) & ~3;            // uint4-aligned block stride

    char* ws = (char*)d_ws;
    size_t off_b = 0;
    auto alloc = [&](size_t bytes) -> void* {
        void* p = ws + off_b;
        off_b = (off_b + bytes + 255) & ~(size_t)255;
        return p;
    };
    size_t csr_entries = (size_t)ne + (size_t)nbk * (BKT_SLACK + 8);

    int*   cnt     = (int*)  alloc((size_t)nn * 4);
    int*   roff    = (int*)  alloc((size_t)nn * 4);
    float* dinv    = (float*)alloc((size_t)nn * 4);
    float* sqd     = (float*)alloc((size_t)nn * 4);
    unsigned char* flag = (unsigned char*)alloc((size_t)nn);
    int*   bktraw  = (int*)  alloc((size_t)MAXNB * 4);
    int*   bktbase = (int*)  alloc((size_t)MAXNB * 4);
    int*   blkhist = (int*)  alloc((size_t)NBLKA * nbk * 4);
    int*   blkboff = (int*)  alloc((size_t)NBLKA * nbk * 4);
    int*   csr     = (int*)  alloc(csr_entries * 4);
    // bin (block-major, consumed by csr_build2) unioned with ya (written by init_y after)
    size_t bin_bytes = (size_t)NBLKA * chunkp * 4;
    size_t y_bytes   = (size_t)(nn + 1) * DIM * 2;   // +1 sentinel zero row
    char*  uni     = (char*) alloc(bin_bytes > y_bytes ? bin_bytes : y_bytes);
    unsigned int* bin = (unsigned int*)uni;
    __half2* ya    = (__half2*)uni;
    __half2* yb    = (__half2*)alloc(y_bytes);
    float* acc     = (float*)alloc((size_t)2 * nb * DIM * 4);

    hipMemsetAsync(flag, 0, (size_t)nn, stream);

    // --- binned CSR build: zero device atomics, fully coalesced global writes ---
    binA1<<<NBLKA, 256, 0, stream>>>(edge_row, blkhist, ne, chunk, nbk);
    binRsum<<<nbk, NBLKA, 0, stream>>>(blkhist, bktraw, nbk);
    binS<<<1, MAXNB, 0, stream>>>(bktraw, bktbase, nbk);
    binA2_sort<<<NBLKA, 256, 0, stream>>>(edge_row, edge_col, blkhist, blkboff, bin,
                                          ne, chunk, chunkp, nbk);
    csr_build2<<<nbk, 256, 0, stream>>>(bin, blkhist, blkboff, bktbase, csr,
                                        cnt, roff, dinv, sqd, nn, nbk, chunkp);

    // --- mark rows whose y2 is consumed (batch + neighbors) ---
    mark_kernel<<<(2 * nb + 3) / 4, 256, 0, stream>>>(cnt, roff, csr, user_idx, item_idx,
                                                      flag, nb, nu);

    // --- init y0 = half(dinv * emb); zero sentinel rows (overwrites bin region) ---
    init_y_kernel<<<((nn + 1) * 32 + 255) / 256, 256, 0, stream>>>(
        (const float2*)user_emb, (const float2*)item_emb, dinv, ya, yb, nu, nn);

    // --- layer 0 acc: exact fp32 embeddings ---
    gather_acc0<<<(2 * nb * DIM + 255) / 256, 256, 0, stream>>>(
        user_emb, item_emb, user_idx, item_idx, acc, nb, nu);

    // --- layer 1 (full) ---
    spmm_half_kernel<<<(nn + 3) / 4, 256, 0, stream>>>(cnt, roff, csr, dinv, ya, yb,
                                                       (const unsigned char*)nullptr, nn);
    gather_acc_y<<<(2 * nb * 32 + 255) / 256, 256, 0, stream>>>(
        yb, sqd, user_idx, item_idx, (float2*)acc, nb, nu);

    // --- layer 2 (restricted to flagged ~69% of rows) ---
    spmm_half_kernel<<<(nn + 3) / 4, 256, 0, stream>>>(cnt, roff, csr, dinv, yb, ya, flag, nn);
    gather_acc_y<<<(2 * nb * 32 + 255) / 256, 256, 0, stream>>>(
        ya, sqd, user_idx, item_idx, (float2*)acc, nb, nu);

    // --- layer 3: only the 8192 batch rows are ever read -> mini-SpMM into acc ---
    spmm_rows_acc_kernel<<<(2 * nb + 3) / 4, 256, 0, stream>>>(
        cnt, roff, csr, dinv, ya, user_idx, item_idx, (float2*)acc, nb, nu);

    scores_kernel<<<(nb + 3) / 4, 256, 0, stream>>>(acc, out, nb);
}

// Round 5
// 353.697 us; speedup vs baseline: 1.2024x; 1.2024x over previous
//
#include <hip/hip_runtime.h>
#include <hip/hip_fp16.h>

#define DIM 64
#define BSH 8            // bucket = row >> 8  (256 rows per bucket)
#define MAXNB 1024       // bucket-count cap (nn <= 256K)
#define NBLKA 1024       // binning blocks (chunk ~3125) -> 4 blocks/CU during binA2
#define BKT_SLACK 1800   // per-bucket slack: 256 rows * 7 pad max + headroom
#define MAXT 11264       // max padded slots per bucket (44KB LDS)

// ---------- A1: per-block bucket histogram (LDS atomics only) ----------
__global__ void binA1(const int* __restrict__ row, int* __restrict__ blkhist,
                      int ne, int chunk, int nbk) {
    __shared__ int h[MAXNB];
    for (int k = threadIdx.x; k < nbk; k += blockDim.x) h[k] = 0;
    __syncthreads();
    int start = blockIdx.x * chunk, end = min(ne, start + chunk);
    for (int i = start + threadIdx.x; i < end; i += blockDim.x)
        atomicAdd(&h[row[i] >> BSH], 1);
    __syncthreads();
    for (int k = threadIdx.x; k < nbk; k += blockDim.x)
        blkhist[blockIdx.x * nbk + k] = h[k];
}

// ---------- R: per-bucket exclusive scan across the 1024 blocks (4 per thread) ----------
__global__ void binR(int* __restrict__ blkhist, int* __restrict__ bktraw, int nbk) {
    __shared__ int ts[256];
    int k = blockIdx.x;
    int b0 = threadIdx.x * 4;
    int v0 = blkhist[(size_t)(b0 + 0) * nbk + k];
    int v1 = blkhist[(size_t)(b0 + 1) * nbk + k];
    int v2 = blkhist[(size_t)(b0 + 2) * nbk + k];
    int v3 = blkhist[(size_t)(b0 + 3) * nbk + k];
    ts[threadIdx.x] = v0 + v1 + v2 + v3;
    __syncthreads();
    for (int d = 1; d < 256; d <<= 1) {
        int t = (threadIdx.x >= d) ? ts[threadIdx.x - d] : 0;
        __syncthreads();
        ts[threadIdx.x] += t;
        __syncthreads();
    }
    int run = (threadIdx.x > 0) ? ts[threadIdx.x - 1] : 0;
    blkhist[(size_t)(b0 + 0) * nbk + k] = run; run += v0;
    blkhist[(size_t)(b0 + 1) * nbk + k] = run; run += v1;
    blkhist[(size_t)(b0 + 2) * nbk + k] = run; run += v2;
    blkhist[(size_t)(b0 + 3) * nbk + k] = run; run += v3;
    if (threadIdx.x == 255) bktraw[k] = run;
}

// ---------- S: exclusive scan of slacked bucket sizes -> bucket bases (x8 aligned) ----------
__global__ void binS(const int* __restrict__ bktraw, int* __restrict__ bktbase, int nbk) {
    __shared__ int s[MAXNB];
    int v = 0;
    if ((int)threadIdx.x < nbk) v = (bktraw[threadIdx.x] + BKT_SLACK + 7) & ~7;
    s[threadIdx.x] = v;
    __syncthreads();
    for (int d = 1; d < MAXNB; d <<= 1) {
        int t = (threadIdx.x >= d) ? s[threadIdx.x - d] : 0;
        __syncthreads();
        s[threadIdx.x] += t;
        __syncthreads();
    }
    if ((int)threadIdx.x < nbk) bktbase[threadIdx.x] = s[threadIdx.x] - v;
}

// ---------- A2: scatter edges into bucket-major bin regions (LDS cursors) ----------
// bin entry: (local_row << 24) | col.  Deterministic per-block start via scanned blkhist;
// 16 waves/CU (1024 blocks) to hide the scattered-store issue latency.
__global__ void binA2(const int* __restrict__ row, const int* __restrict__ col,
                      const int* __restrict__ blkhist, const int* __restrict__ bktbase,
                      unsigned int* __restrict__ bin, int ne, int chunk, int nbk) {
    __shared__ int cur[MAXNB];
    for (int k = threadIdx.x; k < nbk; k += blockDim.x)
        cur[k] = bktbase[k] + blkhist[blockIdx.x * nbk + k];
    __syncthreads();
    int start = blockIdx.x * chunk, end = min(ne, start + chunk);
    for (int i = start + threadIdx.x; i < end; i += blockDim.x) {
        int r = row[i];
        int p = atomicAdd(&cur[r >> BSH], 1);
        bin[p] = ((unsigned)(r & 255) << 24) | (unsigned)col[i];
    }
}

// ---------- B: per-bucket CSR build from CONTIGUOUS bucket region ----------
// rows padded to x8 with sentinel col = nn (points at zero row of y)
__global__ void csr_build(const unsigned int* __restrict__ bin, const int* __restrict__ bktraw,
                          const int* __restrict__ bktbase, int* __restrict__ csr,
                          int* __restrict__ cnt, int* __restrict__ roff,
                          float* __restrict__ dinv, float* __restrict__ sqd, int nn) {
    __shared__ int rc[256];
    __shared__ int sc[256];
    __shared__ int rcur[256];
    __shared__ int Tt;
    __shared__ alignas(16) int scsr[MAXT];
    int k = blockIdx.x;
    int t = threadIdx.x;
    int base = bktbase[k];
    int nraw = bktraw[k];
    rc[t] = 0;
    __syncthreads();
    // pass 1: count rows (contiguous coalesced reads of the bucket region)
    for (int i = t; i < nraw; i += 256)
        atomicAdd(&rc[bin[base + i] >> 24], 1);
    __syncthreads();
    // scan of 8-padded row widths
    int w = (rc[t] + 7) & ~7;
    sc[t] = w;
    __syncthreads();
    for (int d = 1; d < 256; d <<= 1) {
        int v = (t >= d) ? sc[t - d] : 0;
        __syncthreads();
        sc[t] += v;
        __syncthreads();
    }
    int myoff = sc[t] - w;
    if (t == 255) Tt = sc[255];
    rcur[t] = myoff;
    int r = (k << BSH) + t;
    if (r < nn) {
        int d = rc[t];
        cnt[r] = d;
        roff[r] = base + myoff;
        dinv[r] = d > 0 ? rsqrtf((float)d) : 0.0f;
        sqd[r]  = d > 0 ? sqrtf((float)d)  : 0.0f;
    }
    __syncthreads();
    int T = Tt;
    for (int i = t; i < T; i += 256) scsr[i] = nn;   // sentinel -> zero row of y
    __syncthreads();
    // pass 2: place into LDS CSR
    for (int i = t; i < nraw; i += 256) {
        unsigned u = bin[base + i];
        int p = atomicAdd(&rcur[u >> 24], 1);
        scsr[p] = (int)(u & 0xFFFFFFu);
    }
    __syncthreads();
    // coalesced int4 copy to global
    for (int i = t; i * 4 < T; i += 256)
        ((int4*)(csr + base))[i] = ((const int4*)scsr)[i];
}

// ---------- mark rows whose y2 is consumed: batch rows + their neighbors ----------
__global__ void mark_kernel(const int* __restrict__ cnt, const int* __restrict__ off,
                            const int* __restrict__ csr, const int* __restrict__ uidx,
                            const int* __restrict__ iidx, unsigned char* __restrict__ flag,
                            int nb, int nu) {
    int t = blockIdx.x * (blockDim.x >> 6) + (threadIdx.x >> 6);
    int lane = threadIdx.x & 63;
    if (t >= 2 * nb) return;
    int r = (t < nb) ? uidx[t] : nu + iidx[t - nb];
    if (lane == 0) flag[r] = 1;
    int e = cnt[r];
    const int* erow = csr + off[r];
    for (int j = lane; j < e; j += 64) flag[erow[j]] = 1;
}

// ---------- init: y0[r] = half(dinv[r] * emb[r]); sentinel row nn zeroed in BOTH ----------
__global__ void init_y_kernel(const float2* __restrict__ ue2, const float2* __restrict__ ie2,
                              const float* __restrict__ dinv, __half2* __restrict__ ya,
                              __half2* __restrict__ yb, int nu, int nn) {
    int t = blockIdx.x * blockDim.x + threadIdx.x;
    if (t >= (nn + 1) * 32) return;
    int r = t >> 5;
    if (r >= nn) {   // sentinel zero row
        ya[t] = __floats2half2_rn(0.0f, 0.0f);
        yb[t] = __floats2half2_rn(0.0f, 0.0f);
        return;
    }
    float2 v = (r < nu) ? ue2[t] : ie2[t - nu * 32];
    float d = dinv[r];
    ya[t] = __floats2half2_rn(d * v.x, d * v.y);
}

// ---------- paired-half2 gather-SpMM: lane = (edge parity h, feature pair f) ----------
// One 64-lane gather fetches 2 edges x 32 half2 (256B) -> half the VMEM/addr-VALU
// per edge vs one-edge-per-gather. 8-padded sentinel rows -> no tail code.
__global__ void spmm_half_kernel(const int* __restrict__ cnt, const int* __restrict__ off,
                                 const int* __restrict__ csr, const float* __restrict__ dinv,
                                 const __half2* __restrict__ y2, __half2* __restrict__ yn2,
                                 const unsigned char* __restrict__ flag, int nn) {
    int r = blockIdx.x * 4 + (threadIdx.x >> 6);
    if (r >= nn) return;
    if (flag && !flag[r]) return;
    int lane = threadIdx.x & 63;
    int h = lane >> 5;
    int f = lane & 31;
    int e = cnt[r];
    const int* erow = csr + off[r];
    float2 a0 = {0.f, 0.f}, a1 = {0.f, 0.f}, a2 = {0.f, 0.f}, a3 = {0.f, 0.f};
    for (int j = 0; j < e; j += 8) {
        int4 ca = *(const int4*)(erow + j);
        int4 cb = *(const int4*)(erow + j + 4);
        int c0 = h ? ca.y : ca.x;
        int c1 = h ? ca.w : ca.z;
        int c2 = h ? cb.y : cb.x;
        int c3 = h ? cb.w : cb.z;
        float2 p0 = __half22float2(y2[(size_t)c0 * 32 + f]);
        float2 p1 = __half22float2(y2[(size_t)c1 * 32 + f]);
        float2 p2 = __half22float2(y2[(size_t)c2 * 32 + f]);
        float2 p3 = __half22float2(y2[(size_t)c3 * 32 + f]);
        a0.x += p0.x; a0.y += p0.y;
        a1.x += p1.x; a1.y += p1.y;
        a2.x += p2.x; a2.y += p2.y;
        a3.x += p3.x; a3.y += p3.y;
    }
    float sx = (a0.x + a1.x) + (a2.x + a3.x);
    float sy = (a0.y + a1.y) + (a2.y + a3.y);
    sx += __shfl_xor(sx, 32);
    sy += __shfl_xor(sy, 32);
    if (h == 0) {
        float d = dinv[r];
        float d2 = d * d;
        yn2[(size_t)r * 32 + f] = __floats2half2_rn(d2 * sx, d2 * sy);
    }
}

// ---------- layer-3 restricted to the 2*nb batch rows, same paired structure ----------
__global__ void spmm_rows_acc_kernel(const int* __restrict__ cnt, const int* __restrict__ off,
                                     const int* __restrict__ csr, const float* __restrict__ dinv,
                                     const __half2* __restrict__ y2, const int* __restrict__ uidx,
                                     const int* __restrict__ iidx, float2* __restrict__ acc2,
                                     int nb, int nu) {
    int t = blockIdx.x * 4 + (threadIdx.x >> 6);
    if (t >= 2 * nb) return;
    int lane = threadIdx.x & 63;
    int h = lane >> 5;
    int f = lane & 31;
    int r = (t < nb) ? uidx[t] : nu + iidx[t - nb];
    int e = cnt[r];
    const int* erow = csr + off[r];
    float2 a0 = {0.f, 0.f}, a1 = {0.f, 0.f}, a2 = {0.f, 0.f}, a3 = {0.f, 0.f};
    for (int j = 0; j < e; j += 8) {
        int4 ca = *(const int4*)(erow + j);
        int4 cb = *(const int4*)(erow + j + 4);
        int c0 = h ? ca.y : ca.x;
        int c1 = h ? ca.w : ca.z;
        int c2 = h ? cb.y : cb.x;
        int c3 = h ? cb.w : cb.z;
        float2 p0 = __half22float2(y2[(size_t)c0 * 32 + f]);
        float2 p1 = __half22float2(y2[(size_t)c1 * 32 + f]);
        float2 p2 = __half22float2(y2[(size_t)c2 * 32 + f]);
        float2 p3 = __half22float2(y2[(size_t)c3 * 32 + f]);
        a0.x += p0.x; a0.y += p0.y;
        a1.x += p1.x; a1.y += p1.y;
        a2.x += p2.x; a2.y += p2.y;
        a3.x += p3.x; a3.y += p3.y;
    }
    float sx = (a0.x + a1.x) + (a2.x + a3.x);
    float sy = (a0.y + a1.y) + (a2.y + a3.y);
    sx += __shfl_xor(sx, 32);
    sy += __shfl_xor(sy, 32);
    if (h == 0) {
        float d = dinv[r];
        float2 v = acc2[(size_t)t * 32 + f];
        v.x += d * sx;
        v.y += d * sy;
        acc2[(size_t)t * 32 + f] = v;
    }
}

// ---------- layer-0 acc: read embeddings directly (fp32 exact), first write ----------
__global__ void gather_acc0(const float* __restrict__ ue, const float* __restrict__ ie,
                            const int* __restrict__ uidx, const int* __restrict__ iidx,
                            float* __restrict__ acc, int nb, int nu) {
    int t = blockIdx.x * blockDim.x + threadIdx.x;
    int b = t >> 6;
    int lane = t & 63;
    if (b < nb) acc[t] = ue[(long)uidx[b] * DIM + lane];
    else if (b < 2 * nb) acc[t] = ie[(long)iidx[b - nb] * DIM + lane];
}

// ---------- layers 1,2 acc: x_l[r] = y_l[r] * sqrt(deg_r), half2-vectorized ----------
__global__ void gather_acc_y(const __half2* __restrict__ y2, const float* __restrict__ sqd,
                             const int* __restrict__ uidx, const int* __restrict__ iidx,
                             float2* __restrict__ acc2, int nb, int nu) {
    int t = blockIdx.x * blockDim.x + threadIdx.x;
    if (t >= 2 * nb * 32) return;
    int b = t >> 5;
    int r = (b < nb) ? uidx[b] : nu + iidx[b - nb];
    float s = sqd[r];
    float2 v = __half22float2(y2[(size_t)r * 32 + (t & 31)]);
    float2 a = acc2[t];
    a.x += v.x * s;
    a.y += v.y * s;
    acc2[t] = a;
}

// scores[b] = dot(acc_u[b], acc_i[b]) / 16
__global__ void scores_kernel(const float* __restrict__ acc, float* __restrict__ out, int nb) {
    int b = blockIdx.x * (blockDim.x >> 6) + (threadIdx.x >> 6);
    int lane = threadIdx.x & 63;
    if (b >= nb) return;
    float p = acc[(long)b * DIM + lane] * acc[(long)(nb + b) * DIM + lane];
    #pragma unroll
    for (int off = 32; off; off >>= 1) p += __shfl_down(p, off);
    if (lane == 0) out[b] = p * 0.0625f;
}

extern "C" void kernel_launch(void* const* d_in, const int* in_sizes, int n_in,
                              void* d_out, int out_size, void* d_ws, size_t ws_size,
                              hipStream_t stream) {
    const float* user_emb = (const float*)d_in[0];
    const float* item_emb = (const float*)d_in[1];
    const int* edge_row = (const int*)d_in[2];
    const int* edge_col = (const int*)d_in[3];
    const int* user_idx = (const int*)d_in[4];
    const int* item_idx = (const int*)d_in[5];
    float* out = (float*)d_out;

    const int nu = in_sizes[0] / DIM;   // 100000
    const int ni = in_sizes[1] / DIM;   // 50000
    const int nn = nu + ni;             // 150000
    const int ne = in_sizes[2];         // 3200000
    const int nb = in_sizes[4];         // 4096

    const int nbk = (nn + 255) >> BSH;              // 586 buckets
    const int chunk = (ne + NBLKA - 1) / NBLKA;     // 3125

    char* ws = (char*)d_ws;
    size_t off_b = 0;
    auto alloc = [&](size_t bytes) -> void* {
        void* p = ws + off_b;
        off_b = (off_b + bytes + 255) & ~(size_t)255;
        return p;
    };
    size_t csr_entries = (size_t)ne + (size_t)nbk * (BKT_SLACK + 8);

    int*   cnt     = (int*)  alloc((size_t)nn * 4);
    int*   roff    = (int*)  alloc((size_t)nn * 4);
    float* dinv    = (float*)alloc((size_t)nn * 4);
    float* sqd     = (float*)alloc((size_t)nn * 4);
    unsigned char* flag = (unsigned char*)alloc((size_t)nn);
    int*   bktraw  = (int*)  alloc((size_t)MAXNB * 4);
    int*   bktbase = (int*)  alloc((size_t)MAXNB * 4);
    int*   blkhist = (int*)  alloc((size_t)NBLKA * nbk * 4);
    int*   csr     = (int*)  alloc(csr_entries * 4);
    // bin (bucket-major, consumed by csr_build) unioned with ya (written by init_y after)
    size_t bin_bytes = csr_entries * 4;
    size_t y_bytes   = (size_t)(nn + 1) * DIM * 2;   // +1 sentinel zero row
    char*  uni     = (char*) alloc(bin_bytes > y_bytes ? bin_bytes : y_bytes);
    unsigned int* bin = (unsigned int*)uni;
    __half2* ya    = (__half2*)uni;
    __half2* yb    = (__half2*)alloc(y_bytes);
    float* acc     = (float*)alloc((size_t)2 * nb * DIM * 4);

    hipMemsetAsync(flag, 0, (size_t)nn, stream);

    // --- binned CSR build: zero device atomics; bucket-major bin; high-occupancy scatter ---
    binA1<<<NBLKA, 256, 0, stream>>>(edge_row, blkhist, ne, chunk, nbk);
    binR <<<nbk, 256, 0, stream>>>(blkhist, bktraw, nbk);
    binS <<<1, MAXNB, 0, stream>>>(bktraw, bktbase, nbk);
    binA2<<<NBLKA, 256, 0, stream>>>(edge_row, edge_col, blkhist, bktbase, bin, ne, chunk, nbk);
    csr_build<<<nbk, 256, 0, stream>>>(bin, bktraw, bktbase, csr, cnt, roff, dinv, sqd, nn);

    // --- mark rows whose y2 is consumed (batch + neighbors) ---
    mark_kernel<<<(2 * nb + 3) / 4, 256, 0, stream>>>(cnt, roff, csr, user_idx, item_idx,
                                                      flag, nb, nu);

    // --- init y0 = half(dinv * emb); zero sentinel rows (overwrites bin region) ---
    init_y_kernel<<<((nn + 1) * 32 + 255) / 256, 256, 0, stream>>>(
        (const float2*)user_emb, (const float2*)item_emb, dinv, ya, yb, nu, nn);

    // --- layer 0 acc: exact fp32 embeddings ---
    gather_acc0<<<(2 * nb * DIM + 255) / 256, 256, 0, stream>>>(
        user_emb, item_emb, user_idx, item_idx, acc, nb, nu);

    // --- layer 1 (full) ---
    spmm_half_kernel<<<(nn + 3) / 4, 256, 0, stream>>>(cnt, roff, csr, dinv, ya, yb,
                                                       (const unsigned char*)nullptr, nn);
    gather_acc_y<<<(2 * nb * 32 + 255) / 256, 256, 0, stream>>>(
        yb, sqd, user_idx, item_idx, (float2*)acc, nb, nu);

    // --- layer 2 (restricted to flagged ~69% of rows) ---
    spmm_half_kernel<<<(nn + 3) / 4, 256, 0, stream>>>(cnt, roff, csr, dinv, yb, ya, flag, nn);
    gather_acc_y<<<(2 * nb * 32 + 255) / 256, 256, 0, stream>>>(
        ya, sqd, user_idx, item_idx, (float2*)acc, nb, nu);

    // --- layer 3: only the 8192 batch rows are ever read -> mini-SpMM into acc ---
    spmm_rows_acc_kernel<<<(2 * nb + 3) / 4, 256, 0, stream>>>(
        cnt, roff, csr, dinv, ya, user_idx, item_idx, (float2*)acc, nb, nu);

    scores_kernel<<<(nb + 3) / 4, 256, 0, stream>>>(acc, out, nb);
}